// Round 1
// baseline (980.733 us; speedup 1.0000x reference)
//
#include <hip/hip_runtime.h>
#include <hip/hip_bf16.h>

// Problem constants
#define B_TOT   65536
#define IN_DIM  1024
#define NE      4
#define HD      64
#define NTASK   37
#define NC      416      // 256 expert-h cols + 160 gate cols (148 valid, rest zero-pad)
#define NGV     148      // valid gate cols = T*E

typedef float  f32x4 __attribute__((ext_vector_type(4)));
typedef short  s16x8 __attribute__((ext_vector_type(8)));
typedef short  s16x4 __attribute__((ext_vector_type(4)));

typedef __attribute__((address_space(1))) const void gvoid_t;
typedef __attribute__((address_space(3))) void svoid_t;

__device__ __forceinline__ short f2bf(float f){
    union { float f; unsigned u; } a; a.f = f;
    unsigned u = a.u;
    u += 0x7fffu + ((u >> 16) & 1u);   // round-to-nearest-even
    return (short)(u >> 16);
}
__device__ __forceinline__ float bf2f(short s){
    union { unsigned u; float f; } a;
    a.u = ((unsigned)(unsigned short)s) << 16;
    return a.f;
}

// ---------------------------------------------------------------------------
// Prep: pack weights to bf16 in d_ws.
//  Wc  : [32 kchunks][416 n][32 kw]  (combined We1|Wg, B-operand [n][k] layout)
//  We2p: [e][n_out][j_in]            (layer-2, B-operand [n][k] layout)
// ---------------------------------------------------------------------------
__global__ void prep_weights(const float* __restrict__ We1,
                             const float* __restrict__ We2,
                             const float* __restrict__ Wg,
                             short* __restrict__ Wc,
                             short* __restrict__ We2p)
{
    int idx = blockIdx.x * 256 + threadIdx.x;
    const int WC_N = IN_DIM * NC;          // 425984
    if (idx < WC_N){
        int ks = idx / (NC * 32);
        int r  = idx - ks * (NC * 32);
        int n  = r >> 5;
        int k  = ks * 32 + (r & 31);
        float v = 0.f;
        if (n < 256){
            // col n -> expert e = n>>6, unit h = n&63 ; We1 is (E, IN, H)
            v = We1[((size_t)(n >> 6) * IN_DIM + k) * HD + (n & 63)];
        } else if (n < 256 + NGV){
            // gate col g = n-256 -> task t = g>>2, expert e = g&3 ; Wg is (T, IN, E)
            int g = n - 256;
            v = Wg[((size_t)(g >> 2) * IN_DIM + k) * NE + (g & 3)];
        }
        Wc[idx] = f2bf(v);
    } else {
        int j2 = idx - WC_N;
        if (j2 < NE * HD * HD){
            int e = j2 >> 12;
            int rr = j2 & 4095;
            int n = rr >> 6, j = rr & 63;
            // We2 is (E, H_in, H_out): We2p[e][n][j] = We2[e][j][n]
            We2p[j2] = f2bf(We2[((size_t)e * HD + j) * HD + n]);
        }
    }
}

// ---------------------------------------------------------------------------
// Main fused kernel: 64 rows per block, 256 threads (4 waves).
// GEMM x@[We1|Wg] (bf16 MFMA) -> relu/h, in-wave gate softmax,
// layer-2 MFMA, in-lane weighted combine.
// ---------------------------------------------------------------------------
__global__ __launch_bounds__(256)
void mmoe_main(const float* __restrict__ x,
               const float* __restrict__ be1,
               const float* __restrict__ be2,
               const float* __restrict__ bg,
               const short* __restrict__ Wc,
               const short* __restrict__ We2p,
               float* __restrict__ out1,   // (B, T, H)
               float* __restrict__ out2)   // (B, T, E)
{
    __shared__ char lds[53248];
    short* xs   = (short*)lds;              // [64][32]   bf16, GEMM stage
    short* wsm  = (short*)(lds + 4096);     // [416][32]  bf16, GEMM stage
    short* hlds = (short*)lds;              // [64][264]  bf16, h (aliases stage)
    short* glds = (short*)(lds + 33792);    // [64][152]  bf16, gates

    const int tid  = threadIdx.x;
    const int w    = tid >> 6;
    const int lane = tid & 63;
    const int c16  = lane & 15;
    const int quad = lane >> 4;
    const int b0   = blockIdx.x * 64;

    // N-tile split across waves: 7/7/6/6 of 26 tiles
    const int nt_start = (w < 2) ? 7 * w : 14 + 6 * (w - 2);
    const int nt_cnt   = (w < 2) ? 7 : 6;

    f32x4 acc[4][7];
    #pragma unroll
    for (int m = 0; m < 4; ++m)
        #pragma unroll
        for (int j = 0; j < 7; ++j)
            acc[m][j] = f32x4{0.f, 0.f, 0.f, 0.f};

    // x staging assignment: thread -> (row, 8-float k slice)
    const int tr   = tid >> 2;
    const int tcol = (tid & 3) * 8;
    const float* xrow = x + (size_t)(b0 + tr) * IN_DIM + tcol;

    float4 xa = *(const float4*)(xrow);
    float4 xb = *(const float4*)(xrow + 4);

    for (int ks = 0; ks < 32; ++ks){
        __syncthreads();   // previous iteration's LDS reads complete
        // --- stage W chunk: contiguous 26624 B via async global->LDS ---
        const short* wchunk = Wc + ks * (NC * 32);
        #pragma unroll
        for (int i = 0; i < 7; ++i){
            int u = tid + 256 * i;
            if (u < NC * 4)   // 1664 16-byte units
                __builtin_amdgcn_global_load_lds((gvoid_t*)(wchunk + u * 8),
                                                 (svoid_t*)(wsm + u * 8),
                                                 16, 0, 0);
        }
        // --- stage x chunk: fp32 regs -> bf16 -> LDS ---
        s16x8 xv;
        xv[0]=f2bf(xa.x); xv[1]=f2bf(xa.y); xv[2]=f2bf(xa.z); xv[3]=f2bf(xa.w);
        xv[4]=f2bf(xb.x); xv[5]=f2bf(xb.y); xv[6]=f2bf(xb.z); xv[7]=f2bf(xb.w);
        *(s16x8*)(xs + tr * 32 + tcol) = xv;
        __syncthreads();   // staging visible (vmcnt drained by compiler)

        // prefetch next x chunk (hides HBM latency behind this iter's MFMA)
        if (ks < 31){
            xa = *(const float4*)(xrow + (ks + 1) * 32);
            xb = *(const float4*)(xrow + (ks + 1) * 32 + 4);
        }

        // --- compute: A-frags shared across the wave's N tiles ---
        s16x8 af[4];
        #pragma unroll
        for (int m = 0; m < 4; ++m)
            af[m] = *(const s16x8*)(xs + (m * 16 + c16) * 32 + quad * 8);
        #pragma unroll
        for (int j = 0; j < 7; ++j){
            if (j < nt_cnt){
                const int nt = nt_start + j;
                s16x8 bfr = *(const s16x8*)(wsm + (nt * 16 + c16) * 32 + quad * 8);
                #pragma unroll
                for (int m = 0; m < 4; ++m)
                    acc[m][j] = __builtin_amdgcn_mfma_f32_16x16x32_bf16(af[m], bfr, acc[m][j], 0, 0, 0);
            }
        }
    }

    __syncthreads();   // all waves done with stage region before h overwrite

    // ---- epilogue phase 1: relu+bias -> h (LDS bf16), gate softmax ----
    // C layout: col = lane&15, row = quad*4 + reg  [m89/m91]
    #pragma unroll
    for (int j = 0; j < 7; ++j){
        if (j < nt_cnt){
            const int nt  = nt_start + j;
            const int col = nt * 16 + c16;
            if (col < 256){                      // expert-h tile (wave-uniform branch)
                const float b1 = be1[col];
                #pragma unroll
                for (int m = 0; m < 4; ++m){
                    #pragma unroll
                    for (int r = 0; r < 4; ++r){
                        float h = acc[m][j][r] + b1;
                        h = h > 0.f ? h : 0.f;
                        hlds[(m * 16 + quad * 4 + r) * 264 + col] = f2bf(h);
                    }
                }
            } else {                             // gate tile: softmax over 4 adjacent lanes (e = lane&3)
                const int gcol = col - 256;
                const float bgv = (gcol < NGV) ? bg[gcol] : 0.f;
                #pragma unroll
                for (int m = 0; m < 4; ++m){
                    #pragma unroll
                    for (int r = 0; r < 4; ++r){
                        float v  = acc[m][j][r] + bgv;
                        float mx = fmaxf(v, __shfl_xor(v, 1, 64));
                        mx       = fmaxf(mx, __shfl_xor(mx, 2, 64));
                        float p  = __expf(v - mx);
                        float s  = p + __shfl_xor(p, 1, 64);
                        s       += __shfl_xor(s, 2, 64);
                        float g  = p / s;
                        const int row = m * 16 + quad * 4 + r;
                        if (gcol < NGV){
                            __builtin_nontemporal_store(g, &out2[(size_t)(b0 + row) * NGV + gcol]);
                            glds[row * 152 + gcol] = f2bf(g);
                        }
                    }
                }
            }
        }
    }
    __syncthreads();   // h + gates visible

    // ---- layer 2: wave w owns M-tile w (rows m0..m0+15), all 4 experts ----
    const int m0 = w * 16;
    f32x4 acc2[4][4];   // [expert][n-tile]
    #pragma unroll
    for (int e = 0; e < 4; ++e)
        #pragma unroll
        for (int nt = 0; nt < 4; ++nt)
            acc2[e][nt] = f32x4{0.f, 0.f, 0.f, 0.f};

    #pragma unroll
    for (int e = 0; e < 4; ++e){
        #pragma unroll
        for (int s = 0; s < 2; ++s){
            s16x8 ha = *(const s16x8*)(hlds + (m0 + c16) * 264 + e * 64 + s * 32 + quad * 8);
            #pragma unroll
            for (int nt = 0; nt < 4; ++nt){
                s16x8 wb = *(const s16x8*)(We2p + ((size_t)(e * 64 + nt * 16 + c16)) * 64 + s * 32 + quad * 8);
                acc2[e][nt] = __builtin_amdgcn_mfma_f32_16x16x32_bf16(ha, wb, acc2[e][nt], 0, 0, 0);
            }
        }
    }
    // + be2
    #pragma unroll
    for (int e = 0; e < 4; ++e){
        #pragma unroll
        for (int nt = 0; nt < 4; ++nt){
            const float b2 = be2[e * 64 + nt * 16 + c16];
            #pragma unroll
            for (int r = 0; r < 4; ++r)
                acc2[e][nt][r] += b2;
        }
    }

    // ---- combine: out[row][t][h] = sum_e g[row][t][e] * es[row][e][h] ----
    // All 4 expert values for a given (row, hcol) live in THIS lane's acc2.
    for (int t = 0; t < NTASK; ++t){
        #pragma unroll
        for (int r = 0; r < 4; ++r){
            const int row = m0 + quad * 4 + r;
            s16x4 gb = *(const s16x4*)(glds + row * 152 + t * 4);
            const float g0 = bf2f(gb[0]), g1 = bf2f(gb[1]), g2 = bf2f(gb[2]), g3 = bf2f(gb[3]);
            const size_t ob = ((size_t)(b0 + row) * NTASK + t) * HD + c16;
            #pragma unroll
            for (int nt = 0; nt < 4; ++nt){
                float v = g0 * acc2[0][nt][r] + g1 * acc2[1][nt][r]
                        + g2 * acc2[2][nt][r] + g3 * acc2[3][nt][r];
                __builtin_nontemporal_store(v, &out1[ob + nt * 16]);
            }
        }
    }
}

extern "C" void kernel_launch(void* const* d_in, const int* in_sizes, int n_in,
                              void* d_out, int out_size, void* d_ws, size_t ws_size,
                              hipStream_t stream)
{
    const float* x   = (const float*)d_in[0];
    const float* We1 = (const float*)d_in[1];
    const float* be1 = (const float*)d_in[2];
    const float* We2 = (const float*)d_in[3];
    const float* be2 = (const float*)d_in[4];
    const float* Wg  = (const float*)d_in[5];
    const float* bg  = (const float*)d_in[6];

    float* out1 = (float*)d_out;
    float* out2 = out1 + (size_t)B_TOT * NTASK * HD;

    short* Wc   = (short*)d_ws;                       // 425984 bf16
    short* We2p = Wc + (size_t)IN_DIM * NC;           // 16384 bf16 (ws use: ~885 KB)

    const int prep_elems = IN_DIM * NC + NE * HD * HD;  // 442368
    hipLaunchKernelGGL(prep_weights, dim3((prep_elems + 255) / 256), dim3(256), 0, stream,
                       We1, We2, Wg, Wc, We2p);
    hipLaunchKernelGGL(mmoe_main, dim3(B_TOT / 64), dim3(256), 0, stream,
                       x, be1, be2, bg, Wc, We2p, out1, out2);
}